// Round 1
// baseline (272.928 us; speedup 1.0000x reference)
//
#include <hip/hip_runtime.h>

#define S_TOT 16384
#define DD 15
#define HU 1024
#define CHUNK 64
#define WARM 64
#define NROWS (WARM + CHUNK)   // 128

__device__ __forceinline__ float frcp(float x) {
#if __has_builtin(__builtin_amdgcn_rcpf)
  return __builtin_amdgcn_rcpf(x);
#else
  return 1.0f / x;
#endif
}
__device__ __forceinline__ float sigf(float x)  { return frcp(1.0f + __expf(-x)); }
__device__ __forceinline__ float tanha(float x) { return 1.0f - 2.0f * frcp(1.0f + __expf(2.0f * x)); }

// Collapse the linear forecast MLP: M2 = Wf2 @ Wf1  (15x15, stored [i][16-padded]),
// cf = Wf2 @ bf1 + bf2. One wave per output scalar.
__global__ void collapse_k(const float* __restrict__ Wf1, const float* __restrict__ bf1,
                           const float* __restrict__ Wf2, const float* __restrict__ bf2,
                           float* __restrict__ ws) {
  const int task = blockIdx.x;   // 0..239
  const int lane = threadIdx.x;  // 0..63
  float acc = 0.0f;
  if (task < 225) {
    const int i = task / 15, jj = task % 15;
    for (int k = lane; k < 4096; k += 64) acc = fmaf(Wf2[i * 4096 + k], Wf1[k * 15 + jj], acc);
#pragma unroll
    for (int off = 32; off; off >>= 1) acc += __shfl_xor(acc, off, 64);
    if (lane == 0) ws[i * 16 + jj] = acc;
  } else {
    const int i = task - 225;
    for (int k = lane; k < 4096; k += 64) acc = fmaf(Wf2[i * 4096 + k], bf1[k], acc);
#pragma unroll
    for (int off = 32; off; off >>= 1) acc += __shfl_xor(acc, off, 64);
    if (lane == 0) ws[240 + i] = acc + bf2[i];
  }
}

__device__ __forceinline__ float2 block_reduce2(float2 v, float2* slot) {
#pragma unroll
  for (int off = 32; off; off >>= 1) {
    v.x += __shfl_xor(v.x, off, 64);
    v.y += __shfl_xor(v.y, off, 64);
  }
  const int lane = threadIdx.x & 63, wid = threadIdx.x >> 6;
  if (lane == 0) slot[wid] = v;
  __syncthreads();
  float2 r; r.x = 0.0f; r.y = 0.0f;
#pragma unroll
  for (int w = 0; w < 16; ++w) { r.x += slot[w].x; r.y += slot[w].y; }
  return r;
}

__global__ __launch_bounds__(1024)
void lstm_scan_k(const float* __restrict__ x, const float* __restrict__ W_ih,
                 const float* __restrict__ W_hh, const float* __restrict__ b_ih,
                 const float* __restrict__ b_hh, const float* __restrict__ W_hr,
                 const float* __restrict__ ws, float* __restrict__ out) {
  __shared__ float xl[NROWS][16];
  __shared__ float fcl[CHUNK][16];
  __shared__ float m2[15][16];
  __shared__ float cfl[16];
  __shared__ float2 part[2][16];

  const int j = threadIdx.x;            // hidden unit
  const int blk = blockIdx.x;           // time chunk
  const int tmain = blk * CHUNK;
  const int warm = (blk == 0) ? 0 : WARM;
  const int t0 = tmain - warm;
  const int nrows = warm + CHUNK;

  // Per-thread weights in VGPRs (gate order: i, f, g, o per jnp.split).
  float wi[DD], wff[DD], wg[DD], wo[DD];
  const float* r0 = W_ih + (0 * HU + j) * DD;
  const float* r1 = W_ih + (1 * HU + j) * DD;
  const float* r2 = W_ih + (2 * HU + j) * DD;
  const float* r3 = W_ih + (3 * HU + j) * DD;
#pragma unroll
  for (int m = 0; m < DD; ++m) { wi[m] = r0[m]; wff[m] = r1[m]; wg[m] = r2[m]; wo[m] = r3[m]; }
  const float bi = b_ih[j] + b_hh[j];
  const float bf = b_ih[HU + j] + b_hh[HU + j];
  const float bg = b_ih[2 * HU + j] + b_hh[2 * HU + j];
  const float bo = b_ih[3 * HU + j] + b_hh[3 * HU + j];
  const float whi = W_hh[j], whf = W_hh[HU + j], whg = W_hh[2 * HU + j], who = W_hh[3 * HU + j];
  const float wr = W_hr[j];

  // Stage x chunk (+warm-up halo) into LDS.
  for (int idx = j; idx < nrows * DD; idx += 1024) {
    const int tt = idx / DD, m = idx - tt * DD;
    xl[tt][m] = x[(t0 + tt) * DD + m];
  }
  if (j < 240) ((float*)m2)[j] = ws[j];
  if (j < 15) cfl[j] = ws[240 + j];
  __syncthreads();

  // Forecasts for the output steps (also output #2).
  for (int idx = j; idx < CHUNK * DD; idx += 1024) {
    const int tt = idx / DD, i = idx - tt * DD;
    const float* xr = xl[warm + tt];
    float acc = cfl[i];
#pragma unroll
    for (int m = 0; m < DD; ++m) acc = fmaf(m2[i][m], xr[m], acc);
    fcl[tt][i] = acc;
    out[2 * S_TOT + (tmain + tt) * DD + i] = acc;
  }
  __syncthreads();

  float c = 0.0f, h = 0.0f;

  // Warm-up: cell 1 only; converges to true state via forget-gate contraction.
  for (int s = 0; s < warm; ++s) {
    const float* xr = xl[s];
    float gi = bi, gf = bf, gg = bg, go = bo;
#pragma unroll
    for (int m = 0; m < DD; ++m) {
      const float xv = xr[m];
      gi = fmaf(wi[m], xv, gi); gf = fmaf(wff[m], xv, gf);
      gg = fmaf(wg[m], xv, gg); go = fmaf(wo[m], xv, go);
    }
    gi = fmaf(whi, h, gi); gf = fmaf(whf, h, gf);
    gg = fmaf(whg, h, gg); go = fmaf(who, h, go);
    c = sigf(gf) * c + sigf(gi) * tanha(gg);
    float2 v; v.x = wr * (sigf(go) * tanha(c)); v.y = 0.0f;
    h = block_reduce2(v, part[s & 1]).x;
  }

  // Main: cell1(t) + cell2(t-1), one combined float2 reduction per step.
  for (int s = 0; s < CHUNK; ++s) {
    const int t = tmain + s;
    float p2 = 0.0f;
    if (s > 0) {  // cell2 for t-1: uses h1(t-1)=h, c1(t-1)=c (pre-update)
      const float* fr = fcl[s - 1];
      float gi = bi, gf = bf, gg = bg, go = bo;
#pragma unroll
      for (int m = 0; m < DD; ++m) {
        const float fv = fr[m];
        gi = fmaf(wi[m], fv, gi); gf = fmaf(wff[m], fv, gf);
        gg = fmaf(wg[m], fv, gg); go = fmaf(wo[m], fv, go);
      }
      gi = fmaf(whi, h, gi); gf = fmaf(whf, h, gf);
      gg = fmaf(whg, h, gg); go = fmaf(who, h, go);
      const float c2 = sigf(gf) * c + sigf(gi) * tanha(gg);
      p2 = wr * (sigf(go) * tanha(c2));
    }
    // cell1(t)
    const float* xr = xl[warm + s];
    float gi = bi, gf = bf, gg = bg, go = bo;
#pragma unroll
    for (int m = 0; m < DD; ++m) {
      const float xv = xr[m];
      gi = fmaf(wi[m], xv, gi); gf = fmaf(wff[m], xv, gf);
      gg = fmaf(wg[m], xv, gg); go = fmaf(wo[m], xv, go);
    }
    gi = fmaf(whi, h, gi); gf = fmaf(whf, h, gf);
    gg = fmaf(whg, h, gg); go = fmaf(who, h, go);
    c = sigf(gf) * c + sigf(gi) * tanha(gg);
    const float p1 = wr * (sigf(go) * tanha(c));

    float2 v; v.x = p1; v.y = p2;
    const float2 r = block_reduce2(v, part[s & 1]);
    if (j == 0) {
      out[t] = r.x;
      if (s > 0) out[S_TOT + t - 1] = r.y;
    }
    h = r.x;
  }

  // Tail: cell2 for the last main step.
  {
    const float* fr = fcl[CHUNK - 1];
    float gi = bi, gf = bf, gg = bg, go = bo;
#pragma unroll
    for (int m = 0; m < DD; ++m) {
      const float fv = fr[m];
      gi = fmaf(wi[m], fv, gi); gf = fmaf(wff[m], fv, gf);
      gg = fmaf(wg[m], fv, gg); go = fmaf(wo[m], fv, go);
    }
    gi = fmaf(whi, h, gi); gf = fmaf(whf, h, gf);
    gg = fmaf(whg, h, gg); go = fmaf(who, h, go);
    const float c2 = sigf(gf) * c + sigf(gi) * tanha(gg);
    float2 v; v.x = 0.0f; v.y = wr * (sigf(go) * tanha(c2));
    const float2 r = block_reduce2(v, part[0]);
    if (j == 0) out[S_TOT + tmain + CHUNK - 1] = r.y;
  }
}

extern "C" void kernel_launch(void* const* d_in, const int* in_sizes, int n_in,
                              void* d_out, int out_size, void* d_ws, size_t ws_size,
                              hipStream_t stream) {
  const float* x    = (const float*)d_in[0];
  const float* W_ih = (const float*)d_in[1];
  const float* W_hh = (const float*)d_in[2];
  const float* b_ih = (const float*)d_in[3];
  const float* b_hh = (const float*)d_in[4];
  const float* W_hr = (const float*)d_in[5];
  const float* Wf1  = (const float*)d_in[6];
  const float* bf1  = (const float*)d_in[7];
  const float* Wf2  = (const float*)d_in[8];
  const float* bf2  = (const float*)d_in[9];
  float* out = (float*)d_out;
  float* ws  = (float*)d_ws;

  hipLaunchKernelGGL(collapse_k, dim3(240), dim3(64), 0, stream, Wf1, bf1, Wf2, bf2, ws);
  hipLaunchKernelGGL(lstm_scan_k, dim3(256), dim3(1024), 0, stream,
                     x, W_ih, W_hh, b_ih, b_hh, W_hr, ws, out);
}

// Round 2
// 200.344 us; speedup vs baseline: 1.3623x; 1.3623x over previous
//
#include <hip/hip_runtime.h>

#define S_TOT 16384
#define DD 15
#define HU 1024
#define CC 32          // output steps per chunk
#define WW 16          // warm-up steps
#define L2E  1.4426950408889634f
#define L2E2 2.8853900817779268f

__device__ __forceinline__ float rcpf_(float x) { return __builtin_amdgcn_rcpf(x); }
__device__ __forceinline__ float ex2_(float x) {
#if __has_builtin(__builtin_amdgcn_exp2f)
  return __builtin_amdgcn_exp2f(x);
#else
  return exp2f(x);
#endif
}

struct W4 { float4 w[4]; };
struct Cell { float c, p; };

// Gates prescaled: i,f,o by log2e; g by 2*log2e.  sigma(x)=rcp(1+2^-x'), tanh(x)=1-2*rcp(1+2^x'')
__device__ __forceinline__ Cell cellfin(const float4 pre, float h, float c,
                                        const float4 whh, float wr) {
  float ai = fmaf(whh.x, h, pre.x);
  float af = fmaf(whh.y, h, pre.y);
  float ag = fmaf(whh.z, h, pre.z);
  float ao = fmaf(whh.w, h, pre.w);
  float si = rcpf_(1.f + ex2_(-ai));
  float sf = rcpf_(1.f + ex2_(-af));
  float tg = fmaf(-2.f, rcpf_(1.f + ex2_(ag)), 1.f);
  float so = rcpf_(1.f + ex2_(-ao));
  float cn = fmaf(sf, c, si * tg);
  float tc = fmaf(-2.f, rcpf_(1.f + ex2_(cn * L2E2)), 1.f);
  Cell r; r.c = cn; r.p = wr * (so * tc);
  return r;
}

__device__ __forceinline__ float4 gatePre(const float4* __restrict__ row,
    const W4& wI, const W4& wF, const W4& wG, const W4& wO, const float4 bv) {
  float4 r = bv;
#pragma unroll
  for (int q = 0; q < 4; ++q) {
    const float4 xv = row[q];
    r.x = fmaf(wI.w[q].x, xv.x, fmaf(wI.w[q].y, xv.y, fmaf(wI.w[q].z, xv.z, fmaf(wI.w[q].w, xv.w, r.x))));
    r.y = fmaf(wF.w[q].x, xv.x, fmaf(wF.w[q].y, xv.y, fmaf(wF.w[q].z, xv.z, fmaf(wF.w[q].w, xv.w, r.y))));
    r.z = fmaf(wG.w[q].x, xv.x, fmaf(wG.w[q].y, xv.y, fmaf(wG.w[q].z, xv.z, fmaf(wG.w[q].w, xv.w, r.z))));
    r.w = fmaf(wO.w[q].x, xv.x, fmaf(wO.w[q].y, xv.y, fmaf(wO.w[q].z, xv.z, fmaf(wO.w[q].w, xv.w, r.w))));
  }
  return r;
}

// M2 = Wf2 @ Wf1 (15x16-padded) and cf = Wf2 @ bf1 + bf2, 240 blocks x 256 threads.
__global__ void collapse_k(const float* __restrict__ Wf1, const float* __restrict__ bf1,
                           const float* __restrict__ Wf2, const float* __restrict__ bf2,
                           float* __restrict__ ws) {
  __shared__ float red[4];
  const int task = blockIdx.x, tid = threadIdx.x;
  float acc = 0.f;
  if (task < 225) {
    const int i = task / 15, jj = task % 15;
    for (int k = tid; k < 4096; k += 256) acc = fmaf(Wf2[i * 4096 + k], Wf1[k * 15 + jj], acc);
  } else {
    const int i = task - 225;
    for (int k = tid; k < 4096; k += 256) acc = fmaf(Wf2[i * 4096 + k], bf1[k], acc);
  }
#pragma unroll
  for (int off = 32; off; off >>= 1) acc += __shfl_xor(acc, off, 64);
  if (!(tid & 63)) red[tid >> 6] = acc;
  __syncthreads();
  if (tid == 0) {
    float s = red[0] + red[1] + red[2] + red[3];
    if (task < 225) ws[(task / 15) * 16 + (task % 15)] = s;
    else            ws[240 + (task - 225)] = s + bf2[task - 225];
  }
}

__global__ __launch_bounds__(1024)
void lstm_scan_k(const float* __restrict__ x, const float* __restrict__ W_ih,
                 const float* __restrict__ W_hh, const float* __restrict__ b_ih,
                 const float* __restrict__ b_hh, const float* __restrict__ W_hr,
                 const float* __restrict__ ws, float* __restrict__ out) {
  __shared__ __align__(16) float xl[81][16];      // rows t0..t0+79 (+1 guard)
  __shared__ __align__(16) float fcl[2 * CC][16]; // forecasts for both chunks
  __shared__ float m2s[DD][16];
  __shared__ float cfs[16];
  __shared__ __align__(16) float2 partAB[2][16];  // (sum p1A, sum p1B) per wave
  __shared__ __align__(16) float2 part2[2][16];   // (sum p2A, sum p2B) per wave

  const int j = threadIdx.x;
  const int blk = blockIdx.x;
  const int tA = blk * (2 * CC);
  const int tB = tA + CC;
  const int t0 = tA - WW;
  const bool haveA = (blk != 0);

  // ---- per-thread weights (prescaled) ----
  W4 wI, wF, wG, wO;
  {
    const float* p0 = W_ih + (0 * HU + j) * DD;
    const float* p1 = W_ih + (1 * HU + j) * DD;
    const float* p2 = W_ih + (2 * HU + j) * DD;
    const float* p3 = W_ih + (3 * HU + j) * DD;
    float t[4][16];
#pragma unroll
    for (int m = 0; m < DD; ++m) {
      t[0][m] = p0[m] * L2E; t[1][m] = p1[m] * L2E;
      t[2][m] = p2[m] * L2E2; t[3][m] = p3[m] * L2E;
    }
#pragma unroll
    for (int g = 0; g < 4; ++g) t[g][15] = 0.f;
#pragma unroll
    for (int q = 0; q < 4; ++q) {
      wI.w[q] = make_float4(t[0][4 * q], t[0][4 * q + 1], t[0][4 * q + 2], t[0][4 * q + 3]);
      wF.w[q] = make_float4(t[1][4 * q], t[1][4 * q + 1], t[1][4 * q + 2], t[1][4 * q + 3]);
      wG.w[q] = make_float4(t[2][4 * q], t[2][4 * q + 1], t[2][4 * q + 2], t[2][4 * q + 3]);
      wO.w[q] = make_float4(t[3][4 * q], t[3][4 * q + 1], t[3][4 * q + 2], t[3][4 * q + 3]);
    }
  }
  const float4 bv = make_float4((b_ih[j] + b_hh[j]) * L2E,
                                (b_ih[HU + j] + b_hh[HU + j]) * L2E,
                                (b_ih[2 * HU + j] + b_hh[2 * HU + j]) * L2E2,
                                (b_ih[3 * HU + j] + b_hh[3 * HU + j]) * L2E);
  const float4 whh = make_float4(W_hh[j] * L2E, W_hh[HU + j] * L2E,
                                 W_hh[2 * HU + j] * L2E2, W_hh[3 * HU + j] * L2E);
  const float wr = W_hr[j];

  // ---- stage x rows (zero-padded col 15; zero rows before t=0) ----
  for (int idx = j; idx < 80 * 16; idx += 1024) {
    const int r = idx >> 4, m = idx & 15;
    const int t = t0 + r;
    float v = 0.f;
    if (m < 15 && t >= 0) v = x[t * DD + m];
    xl[r][m] = v;
  }
  if (j < 240) ((float*)m2s)[j] = ws[j];
  if (j < 16) cfs[j] = (j < 15) ? ws[240 + j] : 0.f;
  __syncthreads();

  // ---- forecasts for the 64 output rows (also output #2) ----
  for (int idx = j; idx < 64 * 16; idx += 1024) {
    const int tt = idx >> 4, i = idx & 15;
    float v = 0.f;
    if (i < 15) {
      v = cfs[i];
      const float* xr = xl[WW + tt];
#pragma unroll
      for (int m = 0; m < DD; ++m) v = fmaf(m2s[i][m], xr[m], v);
      out[2 * S_TOT + (tA + tt) * DD + i] = v;
    }
    fcl[tt][i] = v;
  }
  __syncthreads();

  const int lane = j & 63, wid = j >> 6;
  float hA = 0.f, hB = 0.f, cA = 0.f, cB = 0.f;
  int buf = 0;

  // ---- warm-up: cell1 only for both chunks (A skipped on blk 0) ----
  float4 pA1 = gatePre((const float4*)xl[0],  wI, wF, wG, wO, bv);
  float4 pB1 = gatePre((const float4*)xl[CC], wI, wF, wG, wO, bv);
  for (int s = 0; s < WW; ++s) {
    float p1A = 0.f, p1B;
    if (haveA) { Cell r = cellfin(pA1, hA, cA, whh, wr); cA = r.c; p1A = r.p; }
    { Cell r = cellfin(pB1, hB, cB, whh, wr); cB = r.c; p1B = r.p; }
    float vx = p1A, vz = p1B;
#pragma unroll
    for (int off = 32; off; off >>= 1) { vx += __shfl_xor(vx, off, 64); vz += __shfl_xor(vz, off, 64); }
    if (!lane) partAB[buf][wid] = make_float2(vx, vz);
    pA1 = gatePre((const float4*)xl[s + 1],      wI, wF, wG, wO, bv);
    pB1 = gatePre((const float4*)xl[CC + s + 1], wI, wF, wG, wO, bv);
    __syncthreads();
    const float4* pp = (const float4*)partAB[buf];
    float sA = 0.f, sB = 0.f;
#pragma unroll
    for (int w = 0; w < 8; ++w) { const float4 q = pp[w]; sA += q.x + q.z; sB += q.y + q.w; }
    hA = sA; hB = sB;
    buf ^= 1;
  }

  // ---- main: 4 cell passes + one reduction/barrier per step ----
  float4 pA2, pB2;
  for (int s = 0; s <= CC; ++s) {
    float p1A = 0.f, p2A = 0.f, p1B = 0.f, p2B = 0.f;
    if (s > 0) {  // cell2 for step s-1: consumes (h1,c1)(s-1), does NOT update state
      Cell r2 = cellfin(pA2, hA, cA, whh, wr); p2A = r2.p;
      Cell r3 = cellfin(pB2, hB, cB, whh, wr); p2B = r3.p;
    }
    if (s < CC) { // cell1 for step s
      Cell r = cellfin(pA1, hA, cA, whh, wr); cA = r.c; p1A = r.p;
      Cell r4 = cellfin(pB1, hB, cB, whh, wr); cB = r4.c; p1B = r4.p;
    }
    float v0 = p1A, v1 = p2A, v2 = p1B, v3 = p2B;
#pragma unroll
    for (int off = 32; off; off >>= 1) {
      v0 += __shfl_xor(v0, off, 64); v1 += __shfl_xor(v1, off, 64);
      v2 += __shfl_xor(v2, off, 64); v3 += __shfl_xor(v3, off, 64);
    }
    if (!lane) { partAB[buf][wid] = make_float2(v0, v2); part2[buf][wid] = make_float2(v1, v3); }
    if (s < CC) {  // prefetch next pre-activations into the tree/barrier shadow
      pA2 = gatePre((const float4*)fcl[s],               wI, wF, wG, wO, bv);
      pB2 = gatePre((const float4*)fcl[CC + s],          wI, wF, wG, wO, bv);
      pA1 = gatePre((const float4*)xl[WW + s + 1],       wI, wF, wG, wO, bv);
      pB1 = gatePre((const float4*)xl[WW + CC + s + 1],  wI, wF, wG, wO, bv);
    }
    __syncthreads();
    const float4* pp = (const float4*)partAB[buf];
    float sA = 0.f, sB = 0.f;
#pragma unroll
    for (int w = 0; w < 8; ++w) { const float4 q = pp[w]; sA += q.x + q.z; sB += q.y + q.w; }
    if (j == 0) {
      if (s < CC) { out[tA + s] = sA; out[tB + s] = sB; }
      if (s > 0) {
        const float4* qq = (const float4*)part2[buf];
        float fA = 0.f, fB = 0.f;
#pragma unroll
        for (int w = 0; w < 8; ++w) { const float4 q = qq[w]; fA += q.x + q.z; fB += q.y + q.w; }
        out[S_TOT + tA + s - 1] = fA; out[S_TOT + tB + s - 1] = fB;
      }
    }
    hA = sA; hB = sB;
    buf ^= 1;
  }
}

extern "C" void kernel_launch(void* const* d_in, const int* in_sizes, int n_in,
                              void* d_out, int out_size, void* d_ws, size_t ws_size,
                              hipStream_t stream) {
  const float* x    = (const float*)d_in[0];
  const float* W_ih = (const float*)d_in[1];
  const float* W_hh = (const float*)d_in[2];
  const float* b_ih = (const float*)d_in[3];
  const float* b_hh = (const float*)d_in[4];
  const float* W_hr = (const float*)d_in[5];
  const float* Wf1  = (const float*)d_in[6];
  const float* bf1  = (const float*)d_in[7];
  const float* Wf2  = (const float*)d_in[8];
  const float* bf2  = (const float*)d_in[9];
  float* out = (float*)d_out;
  float* ws  = (float*)d_ws;

  hipLaunchKernelGGL(collapse_k, dim3(240), dim3(256), 0, stream, Wf1, bf1, Wf2, bf2, ws);
  hipLaunchKernelGGL(lstm_scan_k, dim3(S_TOT / (2 * CC)), dim3(1024), 0, stream,
                     x, W_ih, W_hh, b_ih, b_hh, W_hr, ws, out);
}